// Round 12
// baseline (133.984 us; speedup 1.0000x reference)
//
#include <hip/hip_runtime.h>

// CrumbReconstructor R15: R13 + in-wave software pipelining pinned with
// sched_barrier(0). Attacks the measured bottleneck: intra-wave phase
// serialization (DS burst then VALU burst, ~50% util on BOTH pipes).
//
// R14 post-mortem closed the model: TPK curve 2/3/4 -> 69.5/75.5/72us.
// R13 demands: DS 35us, VALU 37us, measured 72 ~ SUM -> neither pipe
// saturated; bursts don't tile at 3 waves/SIMD. R12 wins only via 6.1
// waves/SIMD which then saturates DS (70.8). R9's ping-pong died because
// the GCN max-occupancy scheduler SINKS prefetch loads (VGPR=32 evidence);
// __builtin_amdgcn_sched_barrier(0) is the documented pin.
//
// Loop body (8 rows = 2 windows), each region fenced:
//   [issue ds_reads W_B] | [compute W_A] | [issue ds_reads W_A'] |
//   [compute W_B]
// -> every load separated from first use by a ~456cy compute region:
// LDS latency + pipe occupancy hide INSIDE one wave; TLP not required.
// Projected max(35,37) + tails = 42-50us.
//
// Exactness identical to R13 (absmax must stay 0.0): same DIST chain
// (mul, 7x fmaf, fmaf(dot,-2,knorm), +rn), same order-independent
// group-4 fmin tree, strict < keeps FIRST winning group, resolve
// recomputes from global with the same op tree, first d == best.

#define LBLK 8          // memblock length
#define NROW 256        // codebook rows
#define BLOCK 64        // 1 wave per block
#define TPK 4           // keys per thread
#define WIN 4           // rows per window / argmin group

__global__ __launch_bounds__(BLOCK, 3) void crumb_kernel(
    const float* __restrict__ x,
    const float* __restrict__ mem,
    float* __restrict__ out,
    int nblocks)
{
    __shared__ float s_mem[NROW * LBLK];            // 8 KB, rows contiguous
    __shared__ __align__(16) float s_norm[NROW];    // 1 KB, b128 window reads

    const int lane = threadIdx.x;

    // --- stage codebook: 4 rows per thread (reads are L2/L3-absorbed) ---
    {
        const float4* g = (const float4*)mem;
        #pragma unroll
        for (int c = 0; c < 4; ++c) {
            const int rr = c * 64 + lane;
            float4 a = g[rr * 2 + 0];
            float4 b = g[rr * 2 + 1];
            ((float4*)s_mem)[rr * 2 + 0] = a;
            ((float4*)s_mem)[rr * 2 + 1] = b;
            float q0 = a.x * a.x, q1 = a.y * a.y, q2 = a.z * a.z, q3 = a.w * a.w;
            float q4 = b.x * b.x, q5 = b.y * b.y, q6 = b.z * b.z, q7 = b.w * b.w;
            s_norm[rr] = ((q0 + q1) + (q2 + q3)) + ((q4 + q5) + (q6 + q7));
        }
    }
    __syncthreads();

    // --- load 4 keys per thread (coalesced per wave) ---
    const long base = (long)blockIdx.x * (BLOCK * TPK) + lane;

    float k[TPK][LBLK];
    float knorm[TPK];

    #pragma unroll
    for (int t = 0; t < TPK; ++t) {
        long b0 = base + (long)t * 64;
        long kbt = (b0 < (long)nblocks) ? b0 : 0;
        const float4* g = (const float4*)(x + kbt * LBLK);
        float4 a = g[0], b = g[1];
        k[t][0] = a.x; k[t][1] = a.y; k[t][2] = a.z; k[t][3] = a.w;
        k[t][4] = b.x; k[t][5] = b.y; k[t][6] = b.z; k[t][7] = b.w;
        float q0 = a.x * a.x, q1 = a.y * a.y, q2 = a.z * a.z, q3 = a.w * a.w;
        float q4 = b.x * b.x, q5 = b.y * b.y, q6 = b.z * b.z, q7 = b.w * b.w;
        knorm[t] = ((q0 + q1) + (q2 + q3)) + ((q4 + q5) + (q6 + q7));
    }

    float best[TPK];
    int   gbs[TPK];
    #pragma unroll
    for (int t = 0; t < TPK; ++t) { best[t] = 3.4e38f; gbs[t] = 0; }

    const float4* sm4 = (const float4*)s_mem;

    // the exact reference distance chain (bit-identical everywhere)
#define DIST(T, RA, RB, RN, DST)                                        \
    {                                                                   \
        float dot = k[(T)][0] * (RA).x;                                 \
        dot = fmaf(k[(T)][1], (RA).y, dot);                             \
        dot = fmaf(k[(T)][2], (RA).z, dot);                             \
        dot = fmaf(k[(T)][3], (RA).w, dot);                             \
        dot = fmaf(k[(T)][4], (RB).x, dot);                             \
        dot = fmaf(k[(T)][5], (RB).y, dot);                             \
        dot = fmaf(k[(T)][6], (RB).z, dot);                             \
        dot = fmaf(k[(T)][7], (RB).w, dot);                             \
        (DST) = fmaf(dot, -2.0f, knorm[(T)]) + (RN);                    \
    }

    // issue all 9 ds_reads of a 4-row window into named registers
#define LOADW(A0, B0, A1, B1, A2, B2, A3, B3, NN, R)                    \
    A0 = sm4[((R) + 0) * 2 + 0]; B0 = sm4[((R) + 0) * 2 + 1];           \
    A1 = sm4[((R) + 1) * 2 + 0]; B1 = sm4[((R) + 1) * 2 + 1];           \
    A2 = sm4[((R) + 2) * 2 + 0]; B2 = sm4[((R) + 2) * 2 + 1];           \
    A3 = sm4[((R) + 3) * 2 + 0]; B3 = sm4[((R) + 3) * 2 + 1];           \
    NN = *(const float4*)&s_norm[(R)];

    // score one window (4 rows) for all TPK keys; group-4 argmin
#define COMPW(A0, B0, A1, B1, A2, B2, A3, B3, NN, R)                    \
    _Pragma("unroll")                                                   \
    for (int t = 0; t < TPK; ++t) {                                     \
        float d0, d1, d2, d3;                                           \
        DIST(t, A0, B0, NN.x, d0);                                      \
        DIST(t, A1, B1, NN.y, d1);                                      \
        DIST(t, A2, B2, NN.z, d2);                                      \
        DIST(t, A3, B3, NN.w, d3);                                      \
        float gm = fminf(fminf(d0, d1), fminf(d2, d3));                 \
        if (gm < best[t]) { best[t] = gm; gbs[t] = (R); }               \
    }

    // --- pipelined scan: 2 windows in flight, regions pinned ---
    float4 wa0, wb0, wa1, wb1, wa2, wb2, wa3, wb3, wn;   // window set A

    LOADW(wa0, wb0, wa1, wb1, wa2, wb2, wa3, wb3, wn, 0);

    #pragma unroll 1
    for (int r = 0; r < NROW; r += 2 * WIN) {
        // region 1: issue loads for window r+4 (set B, body-local)
        float4 ya0, yb0, ya1, yb1, ya2, yb2, ya3, yb3, yn;
        LOADW(ya0, yb0, ya1, yb1, ya2, yb2, ya3, yb3, yn, r + WIN);
        __builtin_amdgcn_sched_barrier(0);
        // region 2: compute window r from set A (loaded last iteration)
        COMPW(wa0, wb0, wa1, wb1, wa2, wb2, wa3, wb3, wn, r);
        __builtin_amdgcn_sched_barrier(0);
        // region 3: issue loads for window r+8 into set A (wraps; unused tail)
        const int rn2 = (r + 2 * WIN) & (NROW - 1);
        LOADW(wa0, wb0, wa1, wb1, wa2, wb2, wa3, wb3, wn, rn2);
        __builtin_amdgcn_sched_barrier(0);
        // region 4: compute window r+4 from set B
        COMPW(ya0, yb0, ya1, yb1, ya2, yb2, ya3, yb3, yn, r + WIN);
        __builtin_amdgcn_sched_barrier(0);
    }
#undef COMPW
#undef LOADW

    // --- resolve + store: recompute winning group from GLOBAL (L1-hot),
    //     take first d == best (lowest index), write its row ---
    #pragma unroll
    for (int t = 0; t < TPK; ++t) {
        long b0 = base + (long)t * 64;
        if (b0 < (long)nblocks) {
            const int gb = gbs[t];
            float4 wa = ((const float4*)(mem + (long)gb * LBLK))[0];
            float4 wb = ((const float4*)(mem + (long)gb * LBLK))[1];
            bool found = false;
            #pragma unroll
            for (int j = 0; j < WIN; ++j) {
                const float4* g = (const float4*)(mem + (long)(gb + j) * LBLK);
                float4 a = g[0], b = g[1];
                // norm recomputed from the same bytes with the same op tree
                float q0 = a.x * a.x, q1 = a.y * a.y, q2 = a.z * a.z, q3 = a.w * a.w;
                float q4 = b.x * b.x, q5 = b.y * b.y, q6 = b.z * b.z, q7 = b.w * b.w;
                float nn = ((q0 + q1) + (q2 + q3)) + ((q4 + q5) + (q6 + q7));
                float d;
                DIST(t, a, b, nn, d);
                bool hit = (d == best[t]) && !found;
                if (hit) { wa = a; wb = b; }
                found = found || (d == best[t]);
            }
            float4* o = (float4*)(out + b0 * LBLK);
            o[0] = wa;
            o[1] = wb;
        }
    }
#undef DIST
}

extern "C" void kernel_launch(void* const* d_in, const int* in_sizes, int n_in,
                              void* d_out, int out_size, void* d_ws, size_t ws_size,
                              hipStream_t stream) {
    const float* x   = (const float*)d_in[0];
    const float* mem = (const float*)d_in[1];
    float* out = (float*)d_out;

    int n = in_sizes[0];            // total x elements
    int nblocks = n / LBLK;         // key-blocks (802816 for std shape)
    int grid = (nblocks + BLOCK * TPK - 1) / (BLOCK * TPK);   // 3136

    hipLaunchKernelGGL(crumb_kernel, dim3(grid), dim3(BLOCK), 0, stream,
                       x, mem, out, nblocks);
}